// Round 6
// baseline (221.384 us; speedup 1.0000x reference)
//
#include <hip/hip_runtime.h>
#include <hip/hip_bf16.h>

typedef __bf16 bf16_t;
typedef __bf16 bf16x8 __attribute__((ext_vector_type(8)));
typedef float f32x4 __attribute__((ext_vector_type(4)));

#define CPOW 1.4426950409e9f           // 1e9 * log2(e)  (exactly representable neighborhood; |s|<ulp/2)
#define QSCALE 0.063758715f            // (1/sqrt(512)) * log2(e)

static __device__ __forceinline__ f32x4 mfma16x16x32(bf16x8 a, bf16x8 b, f32x4 c) {
    return __builtin_amdgcn_mfma_f32_16x16x32_bf16(a, b, c, 0, 0, 0);
}

// ---------------------------------------------------------------------------
// Fused QKV GEMM: for z in {0,1,2}: Out_z[8192,512] = A_z[8192,512] @ W_z[512,512]
// z==0 (Q): epilogue pre-scales by QSCALE (softmax exp2 domain).
// z<2: bf16 row-major out; z==2: bf16 transposed per-batch out[b][col][s] (V).
// ---------------------------------------------------------------------------
__global__ __launch_bounds__(256, 2) void gemm_qkv(
        const float* __restrict__ Aq, const float* __restrict__ Ak, const float* __restrict__ Av,
        const float* __restrict__ Wq, const float* __restrict__ Wk, const float* __restrict__ Wv,
        bf16_t* __restrict__ Oq, bf16_t* __restrict__ Ok, bf16_t* __restrict__ Ov) {
    __shared__ bf16_t As[128][40];
    __shared__ bf16_t Bs[128][40];

    const int tid  = threadIdx.x;
    const int lane = tid & 63;
    const int wave = tid >> 6;
    const int l15  = lane & 15;
    const int kgrp = lane >> 4;
    const int wr   = wave >> 1;
    const int wc   = wave & 1;

    const int row0 = blockIdx.x * 128;
    const int col0 = blockIdx.y * 128;
    const int z    = blockIdx.z;

    const float* A = (z == 0) ? Aq : (z == 1) ? Ak : Av;
    const float* W = (z == 0) ? Wq : (z == 1) ? Wk : Wv;

    const int ar  = tid >> 1;
    const int ach = (tid & 1) * 16;
    const int bc  = tid & 127;
    const int bkh = (tid >> 7) * 16;

    f32x4 acc[4][4];
    #pragma unroll
    for (int m = 0; m < 4; ++m)
        #pragma unroll
        for (int n = 0; n < 4; ++n) acc[m][n] = (f32x4){0.f, 0.f, 0.f, 0.f};

    float4 areg[4];
    float  breg[16];
    const float* Abase = A + (size_t)(row0 + ar) * 512 + ach;
    const float* Wbase = W + (size_t)bkh * 512 + col0 + bc;

    #pragma unroll
    for (int i = 0; i < 4; ++i) areg[i] = *(const float4*)(Abase + i * 4);
    #pragma unroll
    for (int i = 0; i < 16; ++i) breg[i] = Wbase[(size_t)i * 512];

    for (int kb0 = 0; kb0 < 512; kb0 += 32) {
        __syncthreads();
        {
            bf16x8 w0, w1;
            #pragma unroll
            for (int i = 0; i < 4; ++i) { w0[i] = (bf16_t)(&areg[0].x)[i]; w0[i + 4] = (bf16_t)(&areg[1].x)[i]; }
            #pragma unroll
            for (int i = 0; i < 4; ++i) { w1[i] = (bf16_t)(&areg[2].x)[i]; w1[i + 4] = (bf16_t)(&areg[3].x)[i]; }
            *(bf16x8*)&As[ar][ach]     = w0;
            *(bf16x8*)&As[ar][ach + 8] = w1;
            bf16x8 b0, b1;
            #pragma unroll
            for (int i = 0; i < 8; ++i) { b0[i] = (bf16_t)breg[i]; b1[i] = (bf16_t)breg[i + 8]; }
            *(bf16x8*)&Bs[bc][bkh]     = b0;
            *(bf16x8*)&Bs[bc][bkh + 8] = b1;
        }
        __syncthreads();
        if (kb0 + 32 < 512) {
            const float* An = Abase + kb0 + 32;
            #pragma unroll
            for (int i = 0; i < 4; ++i) areg[i] = *(const float4*)(An + i * 4);
            const float* Wn = Wbase + (size_t)(kb0 + 32) * 512;
            #pragma unroll
            for (int i = 0; i < 16; ++i) breg[i] = Wn[(size_t)i * 512];
        }
        bf16x8 af[4], bf[4];
        #pragma unroll
        for (int m = 0; m < 4; ++m) af[m] = *(const bf16x8*)&As[wr * 64 + m * 16 + l15][kgrp * 8];
        #pragma unroll
        for (int n = 0; n < 4; ++n) bf[n] = *(const bf16x8*)&Bs[wc * 64 + n * 16 + l15][kgrp * 8];
        __builtin_amdgcn_s_setprio(1);
        #pragma unroll
        for (int m = 0; m < 4; ++m)
            #pragma unroll
            for (int n = 0; n < 4; ++n)
                acc[m][n] = mfma16x16x32(af[m], bf[n], acc[m][n]);
        __builtin_amdgcn_s_setprio(0);
    }

    bf16_t* O = (z == 0) ? Oq : (z == 1) ? Ok : Ov;
    const float esc = (z == 0) ? QSCALE : 1.0f;
    #pragma unroll
    for (int m = 0; m < 4; ++m)
        #pragma unroll
        for (int j = 0; j < 4; ++j) {
            const int r = row0 + wr * 64 + m * 16 + kgrp * 4 + j;
            #pragma unroll
            for (int n = 0; n < 4; ++n) {
                const int c = col0 + wc * 64 + n * 16 + l15;
                if (z < 2) {
                    O[(size_t)r * 512 + c] = (bf16_t)(acc[m][n][j] * esc);
                } else {
                    const int bb = r >> 10, ss = r & 1023;
                    O[((size_t)bb * 512 + c) * 1024 + ss] = (bf16_t)acc[m][n][j];
                }
            }
        }
}

// ---------------------------------------------------------------------------
// Output GEMM: out[8192,512] = relu(ab @ Wo) * qmask[row],  f32 out.
// ---------------------------------------------------------------------------
__global__ __launch_bounds__(256, 2) void gemm_out(const bf16_t* __restrict__ Ab,
                                                   const float* __restrict__ W,
                                                   float* __restrict__ Out,
                                                   const int* __restrict__ qmask) {
    __shared__ bf16_t As[128][40];
    __shared__ bf16_t Bs[128][40];

    const int tid  = threadIdx.x;
    const int lane = tid & 63;
    const int wave = tid >> 6;
    const int l15  = lane & 15;
    const int kgrp = lane >> 4;
    const int wr   = wave >> 1;
    const int wc   = wave & 1;

    const int row0 = blockIdx.x * 128;
    const int col0 = blockIdx.y * 128;

    const int ar  = tid >> 1;
    const int ach = (tid & 1) * 16;
    const int bc  = tid & 127;
    const int bkh = (tid >> 7) * 16;

    f32x4 acc[4][4];
    #pragma unroll
    for (int m = 0; m < 4; ++m)
        #pragma unroll
        for (int n = 0; n < 4; ++n) acc[m][n] = (f32x4){0.f, 0.f, 0.f, 0.f};

    bf16x8 areg[2];
    float  breg[16];
    const bf16_t* Abase = Ab + (size_t)(row0 + ar) * 512 + ach;
    const float*  Wbase = W + (size_t)bkh * 512 + col0 + bc;

    areg[0] = *(const bf16x8*)Abase;
    areg[1] = *(const bf16x8*)(Abase + 8);
    #pragma unroll
    for (int i = 0; i < 16; ++i) breg[i] = Wbase[(size_t)i * 512];

    for (int kb0 = 0; kb0 < 512; kb0 += 32) {
        __syncthreads();
        *(bf16x8*)&As[ar][ach]     = areg[0];
        *(bf16x8*)&As[ar][ach + 8] = areg[1];
        {
            bf16x8 b0, b1;
            #pragma unroll
            for (int i = 0; i < 8; ++i) { b0[i] = (bf16_t)breg[i]; b1[i] = (bf16_t)breg[i + 8]; }
            *(bf16x8*)&Bs[bc][bkh]     = b0;
            *(bf16x8*)&Bs[bc][bkh + 8] = b1;
        }
        __syncthreads();
        if (kb0 + 32 < 512) {
            const bf16_t* An = Abase + kb0 + 32;
            areg[0] = *(const bf16x8*)An;
            areg[1] = *(const bf16x8*)(An + 8);
            const float* Wn = Wbase + (size_t)(kb0 + 32) * 512;
            #pragma unroll
            for (int i = 0; i < 16; ++i) breg[i] = Wn[(size_t)i * 512];
        }
        bf16x8 af[4], bf[4];
        #pragma unroll
        for (int m = 0; m < 4; ++m) af[m] = *(const bf16x8*)&As[wr * 64 + m * 16 + l15][kgrp * 8];
        #pragma unroll
        for (int n = 0; n < 4; ++n) bf[n] = *(const bf16x8*)&Bs[wc * 64 + n * 16 + l15][kgrp * 8];
        __builtin_amdgcn_s_setprio(1);
        #pragma unroll
        for (int m = 0; m < 4; ++m)
            #pragma unroll
            for (int n = 0; n < 4; ++n)
                acc[m][n] = mfma16x16x32(af[m], bf[n], acc[m][n]);
        __builtin_amdgcn_s_setprio(0);
    }

    #pragma unroll
    for (int m = 0; m < 4; ++m)
        #pragma unroll
        for (int j = 0; j < 4; ++j) {
            const int r = row0 + wr * 64 + m * 16 + kgrp * 4 + j;
            const float fq = (float)qmask[r];
            #pragma unroll
            for (int n = 0; n < 4; ++n) {
                const int c = col0 + wc * 64 + n * 16 + l15;
                Out[(size_t)r * 512 + c] = fmaxf(acc[m][n][j], 0.0f) * fq;
            }
        }
}

// ---------------------------------------------------------------------------
// Flash attention, split-K across 4 waves (round-4 structure). Block = 256 thr,
// ONE 32-row q-chunk per block; wave w processes K-tiles {w, w+4, ...}; exact
// block-level softmax merge through bf16 LDS at the end.
// LDS 19.5 KB + VGPR<=85 -> __launch_bounds__(256,6): 6 blocks/CU.
// Q pre-scaled by QSCALE; softmax in exp2 domain; masks subtract CPOW
// (ties exact: masked scores are exactly -CPOW / -2*CPOW).
// grid = (64 hb, 32): id%8 = b -> per-XCD batch locality; heavy chunks first.
// ---------------------------------------------------------------------------
__global__ __launch_bounds__(256, 6) void attn_flash(const bf16_t* __restrict__ qb,
                                                     const bf16_t* __restrict__ kb,
                                                     const bf16_t* __restrict__ vtb,
                                                     const int* __restrict__ key_mask,
                                                     bf16_t* __restrict__ attout) {
    __shared__ char shbuf[19456];
    bf16_t (*P)[32][72]   = (bf16_t(*)[32][72])shbuf;   // per-wave P tiles (18432 B)
    bf16_t (*Omg)[32][72] = (bf16_t(*)[32][72])shbuf;   // merge O (aliases P, after barrier)
    float* mmg = (float*)(shbuf + 18432);               // 4*32 floats
    float* lmg = (float*)(shbuf + 18432 + 512);         // 4*32 floats

    const int tid  = threadIdx.x;
    const int lane = tid & 63;
    const int w    = tid >> 6;     // wave id = K-slice
    const int l15  = lane & 15;
    const int kgrp = lane >> 4;

    const int hb = blockIdx.x;
    const int h  = hb >> 3;
    const int b  = hb & 7;
    const int qw = (31 - (int)blockIdx.y) * 32;

    const size_t bS512 = (size_t)b * 1024 * 512;
    const int hoff = h * 64;
    const int* km = key_mask + h * 1024;

    int kmv = km[lane];
    unsigned long long bal = __ballot(kmv != 0);
    int first1 = bal ? (__ffsll(bal) - 1) : 64;
    const int ntiles = (qw < first1) ? 16 : ((qw + 95) >> 6);

    bf16x8 aq[2][2];
    #pragma unroll
    for (int rf = 0; rf < 2; ++rf)
        #pragma unroll
        for (int ks = 0; ks < 2; ++ks)
            aq[rf][ks] = *(const bf16x8*)(qb + bS512 + (size_t)(qw + rf * 16 + l15) * 512
                                          + hoff + ks * 32 + kgrp * 8);

    f32x4 O[2][4];
    float m[2][4], l[2][4];
    #pragma unroll
    for (int rf = 0; rf < 2; ++rf) {
        #pragma unroll
        for (int df = 0; df < 4; ++df) O[rf][df] = (f32x4){0.f, 0.f, 0.f, 0.f};
        #pragma unroll
        for (int j = 0; j < 4; ++j) { m[rf][j] = -3.0e38f; l[rf][j] = 0.f; }
    }

    const bf16_t* kbase = kb + bS512 + hoff;
    const bf16_t* vbase = vtb + ((size_t)b * 512 + hoff) * 1024;

    for (int kt = w; kt < ntiles; kt += 4) {
        const int kt0 = kt * 64;

        // ---- QK^T (Q pre-scaled) ----
        f32x4 S[2][4];
        #pragma unroll
        for (int rf = 0; rf < 2; ++rf)
            #pragma unroll
            for (int cf = 0; cf < 4; ++cf) S[rf][cf] = (f32x4){0.f, 0.f, 0.f, 0.f};

        __builtin_amdgcn_s_setprio(1);
        #pragma unroll
        for (int cf = 0; cf < 4; ++cf) {
            const bf16_t* krow = kbase + (size_t)(kt0 + cf * 16 + l15) * 512 + kgrp * 8;
            bf16x8 bk0 = *(const bf16x8*)krow;
            bf16x8 bk1 = *(const bf16x8*)(krow + 32);
            S[0][cf] = mfma16x16x32(aq[0][0], bk0, S[0][cf]);
            S[0][cf] = mfma16x16x32(aq[0][1], bk1, S[0][cf]);
            S[1][cf] = mfma16x16x32(aq[1][0], bk0, S[1][cf]);
            S[1][cf] = mfma16x16x32(aq[1][1], bk1, S[1][cf]);
        }
        __builtin_amdgcn_s_setprio(0);

        // ---- masks (exp2 domain, exact ties) + per-lane max ----
        float kmadd[4];
        #pragma unroll
        for (int cf = 0; cf < 4; ++cf)
            kmadd[cf] = (km[kt0 + cf * 16 + l15] == 0) ? CPOW : 0.0f;

        const bool needC = (kt0 + 63 > qw);
        float mx[2][4];
        #pragma unroll
        for (int rf = 0; rf < 2; ++rf)
            #pragma unroll
            for (int j = 0; j < 4; ++j) {
                const int qrow = qw + rf * 16 + kgrp * 4 + j;
                float mj = -3.0e38f;
                #pragma unroll
                for (int cf = 0; cf < 4; ++cf) {
                    float sub = kmadd[cf];
                    if (needC && (kt0 + cf * 16 + l15 > qrow)) sub += CPOW;
                    float s = S[rf][cf][j] - sub;
                    S[rf][cf][j] = s;
                    mj = fmaxf(mj, s);
                }
                mx[rf][j] = mj;
            }
        #pragma unroll
        for (int off = 1; off < 16; off <<= 1)
            #pragma unroll
            for (int rf = 0; rf < 2; ++rf)
                #pragma unroll
                for (int j = 0; j < 4; ++j)
                    mx[rf][j] = fmaxf(mx[rf][j], __shfl_xor(mx[rf][j], off));

        // ---- online update (l kept per-lane partial) ----
        float fac[2][4];
        #pragma unroll
        for (int rf = 0; rf < 2; ++rf)
            #pragma unroll
            for (int j = 0; j < 4; ++j) {
                float mn = fmaxf(m[rf][j], mx[rf][j]);
                fac[rf][j] = __builtin_amdgcn_exp2f(m[rf][j] - mn);
                m[rf][j] = mn;
            }
        #pragma unroll
        for (int rf = 0; rf < 2; ++rf)
            #pragma unroll
            for (int j = 0; j < 4; ++j) {
                float ps = 0.f;
                #pragma unroll
                for (int cf = 0; cf < 4; ++cf) {
                    float p = __builtin_amdgcn_exp2f(S[rf][cf][j] - m[rf][j]);
                    S[rf][cf][j] = p;
                    ps += p;
                }
                l[rf][j] = l[rf][j] * fac[rf][j] + ps;
            }
        #pragma unroll
        for (int rf = 0; rf < 2; ++rf)
            #pragma unroll
            for (int df = 0; df < 4; ++df)
                #pragma unroll
                for (int j = 0; j < 4; ++j)
                    O[rf][df][j] *= fac[rf][j];

        // ---- P -> per-wave LDS tile, wave-local wait ----
        #pragma unroll
        for (int rf = 0; rf < 2; ++rf)
            #pragma unroll
            for (int cf = 0; cf < 4; ++cf)
                #pragma unroll
                for (int j = 0; j < 4; ++j)
                    P[w][rf * 16 + kgrp * 4 + j][cf * 16 + l15] = (bf16_t)S[rf][cf][j];
        asm volatile("s_waitcnt lgkmcnt(0)" ::: "memory");

        bf16x8 pa[2][2];
        #pragma unroll
        for (int rf = 0; rf < 2; ++rf)
            #pragma unroll
            for (int ks = 0; ks < 2; ++ks)
                pa[rf][ks] = *(const bf16x8*)&P[w][rf * 16 + l15][ks * 32 + kgrp * 8];

        // ---- PV ----
        __builtin_amdgcn_s_setprio(1);
        #pragma unroll
        for (int df = 0; df < 4; ++df) {
            const bf16_t* vrow = vbase + (size_t)(df * 16 + l15) * 1024 + kt0 + kgrp * 8;
            bf16x8 vf0 = *(const bf16x8*)vrow;
            bf16x8 vf1 = *(const bf16x8*)(vrow + 32);
            O[0][df] = mfma16x16x32(pa[0][0], vf0, O[0][df]);
            O[0][df] = mfma16x16x32(pa[0][1], vf1, O[0][df]);
            O[1][df] = mfma16x16x32(pa[1][0], vf0, O[1][df]);
            O[1][df] = mfma16x16x32(pa[1][1], vf1, O[1][df]);
        }
        __builtin_amdgcn_s_setprio(0);
    }

    // ---- merge phase ----
    __syncthreads();   // all waves done with P region

    #pragma unroll
    for (int rf = 0; rf < 2; ++rf)
        #pragma unroll
        for (int j = 0; j < 4; ++j) {
            float lv = l[rf][j];
            #pragma unroll
            for (int off = 1; off < 16; off <<= 1) lv += __shfl_xor(lv, off);
            l[rf][j] = lv;
        }

    #pragma unroll
    for (int rf = 0; rf < 2; ++rf)
        #pragma unroll
        for (int df = 0; df < 4; ++df)
            #pragma unroll
            for (int j = 0; j < 4; ++j)
                Omg[w][rf * 16 + kgrp * 4 + j][df * 16 + l15] = (bf16_t)O[rf][df][j];
    if (l15 == 0) {
        #pragma unroll
        for (int rf = 0; rf < 2; ++rf)
            #pragma unroll
            for (int j = 0; j < 4; ++j) {
                mmg[w * 32 + rf * 16 + kgrp * 4 + j] = m[rf][j];
                lmg[w * 32 + rf * 16 + kgrp * 4 + j] = l[rf][j];
            }
    }
    __syncthreads();

    {
        const int r  = tid >> 3;        // 0..31
        const int c0 = (tid & 7) * 8;   // 0..56
        float m0 = mmg[r], m1 = mmg[32 + r], m2 = mmg[64 + r], m3 = mmg[96 + r];
        float M = fmaxf(fmaxf(m0, m1), fmaxf(m2, m3));
        float f0 = __builtin_amdgcn_exp2f(m0 - M), f1 = __builtin_amdgcn_exp2f(m1 - M);
        float f2 = __builtin_amdgcn_exp2f(m2 - M), f3 = __builtin_amdgcn_exp2f(m3 - M);
        float ls = lmg[r] * f0 + lmg[32 + r] * f1 + lmg[64 + r] * f2 + lmg[96 + r] * f3;
        float inv = 1.0f / ls;
        bf16x8 o0 = *(const bf16x8*)&Omg[0][r][c0];
        bf16x8 o1 = *(const bf16x8*)&Omg[1][r][c0];
        bf16x8 o2 = *(const bf16x8*)&Omg[2][r][c0];
        bf16x8 o3 = *(const bf16x8*)&Omg[3][r][c0];
        bf16_t outv[8];
        #pragma unroll
        for (int i = 0; i < 8; ++i) {
            float acc = (float)o0[i] * f0 + (float)o1[i] * f1
                      + (float)o2[i] * f2 + (float)o3[i] * f3;
            outv[i] = (bf16_t)(acc * inv);
        }
        *(bf16x8*)&attout[(size_t)(h * 1024 + qw + r) * 512 + b * 64 + c0] = *(bf16x8*)outv;
    }
}

// ---------------------------------------------------------------------------
extern "C" void kernel_launch(void* const* d_in, const int* in_sizes, int n_in,
                              void* d_out, int out_size, void* d_ws, size_t ws_size,
                              hipStream_t stream) {
    const float* query = (const float*)d_in[0];
    const float* key   = (const float*)d_in[1];
    const float* value = (const float*)d_in[2];
    const int*   qmask = (const int*)d_in[3];
    const int*   kmask = (const int*)d_in[4];
    const float* Wq    = (const float*)d_in[5];
    const float* Wk    = (const float*)d_in[6];
    const float* Wv    = (const float*)d_in[7];
    const float* Wo    = (const float*)d_in[8];
    float* out = (float*)d_out;

    const size_t NELEM = (size_t)8 * 1024 * 512;
    bf16_t* qb  = (bf16_t*)d_ws;
    bf16_t* kb  = qb + NELEM;
    bf16_t* vtb = kb + NELEM;   // [b][d(512)][s(1024)]
    bf16_t* ab  = vtb + NELEM;

    gemm_qkv<<<dim3(64, 4, 3), dim3(256), 0, stream>>>(query, key, value, Wq, Wk, Wv, qb, kb, vtb);
    attn_flash<<<dim3(64, 32), dim3(256), 0, stream>>>(qb, kb, vtb, kmask, ab);
    gemm_out<<<dim3(64, 4), dim3(256), 0, stream>>>(ab, Wo, out, qmask);
}

// Round 7
// 173.265 us; speedup vs baseline: 1.2777x; 1.2777x over previous
//
#include <hip/hip_runtime.h>
#include <hip/hip_bf16.h>

typedef __bf16 bf16_t;
typedef __bf16 bf16x8 __attribute__((ext_vector_type(8)));
typedef float f32x4 __attribute__((ext_vector_type(4)));

#define CPOW 1.4426950409e9f           // 1e9 * log2(e)  (masked scores round to exactly -CPOW/-2CPOW)
#define QSCALE 0.063758715f            // (1/sqrt(512)) * log2(e)

static __device__ __forceinline__ f32x4 mfma16x16x32(bf16x8 a, bf16x8 b, f32x4 c) {
    return __builtin_amdgcn_mfma_f32_16x16x32_bf16(a, b, c, 0, 0, 0);
}

// ---------------------------------------------------------------------------
// Fused QKV GEMM: for z in {0,1,2}: Out_z[8192,512] = A_z[8192,512] @ W_z[512,512]
// z==0 (Q): epilogue pre-scales by QSCALE (softmax exp2 domain).
// z<2: bf16 row-major out; z==2: bf16 transposed per-batch out[b][col][s] (V).
// ---------------------------------------------------------------------------
__global__ __launch_bounds__(256, 2) void gemm_qkv(
        const float* __restrict__ Aq, const float* __restrict__ Ak, const float* __restrict__ Av,
        const float* __restrict__ Wq, const float* __restrict__ Wk, const float* __restrict__ Wv,
        bf16_t* __restrict__ Oq, bf16_t* __restrict__ Ok, bf16_t* __restrict__ Ov) {
    __shared__ bf16_t As[128][40];
    __shared__ bf16_t Bs[128][40];

    const int tid  = threadIdx.x;
    const int lane = tid & 63;
    const int wave = tid >> 6;
    const int l15  = lane & 15;
    const int kgrp = lane >> 4;
    const int wr   = wave >> 1;
    const int wc   = wave & 1;

    const int row0 = blockIdx.x * 128;
    const int col0 = blockIdx.y * 128;
    const int z    = blockIdx.z;

    const float* A = (z == 0) ? Aq : (z == 1) ? Ak : Av;
    const float* W = (z == 0) ? Wq : (z == 1) ? Wk : Wv;

    const int ar  = tid >> 1;
    const int ach = (tid & 1) * 16;
    const int bc  = tid & 127;
    const int bkh = (tid >> 7) * 16;

    f32x4 acc[4][4];
    #pragma unroll
    for (int m = 0; m < 4; ++m)
        #pragma unroll
        for (int n = 0; n < 4; ++n) acc[m][n] = (f32x4){0.f, 0.f, 0.f, 0.f};

    float4 areg[4];
    float  breg[16];
    const float* Abase = A + (size_t)(row0 + ar) * 512 + ach;
    const float* Wbase = W + (size_t)bkh * 512 + col0 + bc;

    #pragma unroll
    for (int i = 0; i < 4; ++i) areg[i] = *(const float4*)(Abase + i * 4);
    #pragma unroll
    for (int i = 0; i < 16; ++i) breg[i] = Wbase[(size_t)i * 512];

    for (int kb0 = 0; kb0 < 512; kb0 += 32) {
        __syncthreads();
        {
            bf16x8 w0, w1;
            #pragma unroll
            for (int i = 0; i < 4; ++i) { w0[i] = (bf16_t)(&areg[0].x)[i]; w0[i + 4] = (bf16_t)(&areg[1].x)[i]; }
            #pragma unroll
            for (int i = 0; i < 4; ++i) { w1[i] = (bf16_t)(&areg[2].x)[i]; w1[i + 4] = (bf16_t)(&areg[3].x)[i]; }
            *(bf16x8*)&As[ar][ach]     = w0;
            *(bf16x8*)&As[ar][ach + 8] = w1;
            bf16x8 b0, b1;
            #pragma unroll
            for (int i = 0; i < 8; ++i) { b0[i] = (bf16_t)breg[i]; b1[i] = (bf16_t)breg[i + 8]; }
            *(bf16x8*)&Bs[bc][bkh]     = b0;
            *(bf16x8*)&Bs[bc][bkh + 8] = b1;
        }
        __syncthreads();
        if (kb0 + 32 < 512) {
            const float* An = Abase + kb0 + 32;
            #pragma unroll
            for (int i = 0; i < 4; ++i) areg[i] = *(const float4*)(An + i * 4);
            const float* Wn = Wbase + (size_t)(kb0 + 32) * 512;
            #pragma unroll
            for (int i = 0; i < 16; ++i) breg[i] = Wn[(size_t)i * 512];
        }
        bf16x8 af[4], bf[4];
        #pragma unroll
        for (int m = 0; m < 4; ++m) af[m] = *(const bf16x8*)&As[wr * 64 + m * 16 + l15][kgrp * 8];
        #pragma unroll
        for (int n = 0; n < 4; ++n) bf[n] = *(const bf16x8*)&Bs[wc * 64 + n * 16 + l15][kgrp * 8];
        __builtin_amdgcn_s_setprio(1);
        #pragma unroll
        for (int m = 0; m < 4; ++m)
            #pragma unroll
            for (int n = 0; n < 4; ++n)
                acc[m][n] = mfma16x16x32(af[m], bf[n], acc[m][n]);
        __builtin_amdgcn_s_setprio(0);
    }

    bf16_t* O = (z == 0) ? Oq : (z == 1) ? Ok : Ov;
    const float esc = (z == 0) ? QSCALE : 1.0f;
    #pragma unroll
    for (int m = 0; m < 4; ++m)
        #pragma unroll
        for (int j = 0; j < 4; ++j) {
            const int r = row0 + wr * 64 + m * 16 + kgrp * 4 + j;
            #pragma unroll
            for (int n = 0; n < 4; ++n) {
                const int c = col0 + wc * 64 + n * 16 + l15;
                if (z < 2) {
                    O[(size_t)r * 512 + c] = (bf16_t)(acc[m][n][j] * esc);
                } else {
                    const int bb = r >> 10, ss = r & 1023;
                    O[((size_t)bb * 512 + c) * 1024 + ss] = (bf16_t)acc[m][n][j];
                }
            }
        }
}

// ---------------------------------------------------------------------------
// Output GEMM: out[8192,512] = relu(ab @ Wo) * qmask[row],  f32 out.
// ---------------------------------------------------------------------------
__global__ __launch_bounds__(256, 2) void gemm_out(const bf16_t* __restrict__ Ab,
                                                   const float* __restrict__ W,
                                                   float* __restrict__ Out,
                                                   const int* __restrict__ qmask) {
    __shared__ bf16_t As[128][40];
    __shared__ bf16_t Bs[128][40];

    const int tid  = threadIdx.x;
    const int lane = tid & 63;
    const int wave = tid >> 6;
    const int l15  = lane & 15;
    const int kgrp = lane >> 4;
    const int wr   = wave >> 1;
    const int wc   = wave & 1;

    const int row0 = blockIdx.x * 128;
    const int col0 = blockIdx.y * 128;

    const int ar  = tid >> 1;
    const int ach = (tid & 1) * 16;
    const int bc  = tid & 127;
    const int bkh = (tid >> 7) * 16;

    f32x4 acc[4][4];
    #pragma unroll
    for (int m = 0; m < 4; ++m)
        #pragma unroll
        for (int n = 0; n < 4; ++n) acc[m][n] = (f32x4){0.f, 0.f, 0.f, 0.f};

    bf16x8 areg[2];
    float  breg[16];
    const bf16_t* Abase = Ab + (size_t)(row0 + ar) * 512 + ach;
    const float*  Wbase = W + (size_t)bkh * 512 + col0 + bc;

    areg[0] = *(const bf16x8*)Abase;
    areg[1] = *(const bf16x8*)(Abase + 8);
    #pragma unroll
    for (int i = 0; i < 16; ++i) breg[i] = Wbase[(size_t)i * 512];

    for (int kb0 = 0; kb0 < 512; kb0 += 32) {
        __syncthreads();
        *(bf16x8*)&As[ar][ach]     = areg[0];
        *(bf16x8*)&As[ar][ach + 8] = areg[1];
        {
            bf16x8 b0, b1;
            #pragma unroll
            for (int i = 0; i < 8; ++i) { b0[i] = (bf16_t)breg[i]; b1[i] = (bf16_t)breg[i + 8]; }
            *(bf16x8*)&Bs[bc][bkh]     = b0;
            *(bf16x8*)&Bs[bc][bkh + 8] = b1;
        }
        __syncthreads();
        if (kb0 + 32 < 512) {
            const bf16_t* An = Abase + kb0 + 32;
            areg[0] = *(const bf16x8*)An;
            areg[1] = *(const bf16x8*)(An + 8);
            const float* Wn = Wbase + (size_t)(kb0 + 32) * 512;
            #pragma unroll
            for (int i = 0; i < 16; ++i) breg[i] = Wn[(size_t)i * 512];
        }
        bf16x8 af[4], bf[4];
        #pragma unroll
        for (int m = 0; m < 4; ++m) af[m] = *(const bf16x8*)&As[wr * 64 + m * 16 + l15][kgrp * 8];
        #pragma unroll
        for (int n = 0; n < 4; ++n) bf[n] = *(const bf16x8*)&Bs[wc * 64 + n * 16 + l15][kgrp * 8];
        __builtin_amdgcn_s_setprio(1);
        #pragma unroll
        for (int m = 0; m < 4; ++m)
            #pragma unroll
            for (int n = 0; n < 4; ++n)
                acc[m][n] = mfma16x16x32(af[m], bf[n], acc[m][n]);
        __builtin_amdgcn_s_setprio(0);
    }

    #pragma unroll
    for (int m = 0; m < 4; ++m)
        #pragma unroll
        for (int j = 0; j < 4; ++j) {
            const int r = row0 + wr * 64 + m * 16 + kgrp * 4 + j;
            const float fq = (float)qmask[r];
            #pragma unroll
            for (int n = 0; n < 4; ++n) {
                const int c = col0 + wc * 64 + n * 16 + l15;
                Out[(size_t)r * 512 + c] = fmaxf(acc[m][n][j], 0.0f) * fq;
            }
        }
}

// ---------------------------------------------------------------------------
// Flash attention, split-K across 4 waves. Block = 256 thr, ONE 32-row q-chunk;
// wave w processes K-tiles {w, w+4, ...}; exact block-level softmax merge
// through bf16 LDS at the end.
// __launch_bounds__(256,5): VGPR cap 102 > ~84 natural -> NO SPILL (R6 lesson:
// (256,6) cap 85 made the allocator collapse to 40 VGPR + scratch, FETCH 255MB).
// LDS 19.5 KB -> up to 6 blocks/CU by LDS; expect ~5 by VGPR.
// grid = (64 hb, 32): id%8 = b -> per-XCD batch locality; heavy chunks first.
// ---------------------------------------------------------------------------
__global__ __launch_bounds__(256, 5) void attn_flash(const bf16_t* __restrict__ qb,
                                                     const bf16_t* __restrict__ kb,
                                                     const bf16_t* __restrict__ vtb,
                                                     const int* __restrict__ key_mask,
                                                     bf16_t* __restrict__ attout) {
    __shared__ char shbuf[19456];
    bf16_t (*P)[32][72]   = (bf16_t(*)[32][72])shbuf;   // per-wave P tiles (18432 B)
    bf16_t (*Omg)[32][72] = (bf16_t(*)[32][72])shbuf;   // merge O (aliases P, after barrier)
    float* mmg = (float*)(shbuf + 18432);               // 4*32 floats
    float* lmg = (float*)(shbuf + 18432 + 512);         // 4*32 floats

    const int tid  = threadIdx.x;
    const int lane = tid & 63;
    const int w    = tid >> 6;     // wave id = K-slice
    const int l15  = lane & 15;
    const int kgrp = lane >> 4;

    const int hb = blockIdx.x;
    const int h  = hb >> 3;
    const int b  = hb & 7;
    const int qw = (31 - (int)blockIdx.y) * 32;

    const size_t bS512 = (size_t)b * 1024 * 512;
    const int hoff = h * 64;
    const int* km = key_mask + h * 1024;

    int kmv = km[lane];
    unsigned long long bal = __ballot(kmv != 0);
    int first1 = bal ? (__ffsll(bal) - 1) : 64;
    const int ntiles = (qw < first1) ? 16 : ((qw + 95) >> 6);

    bf16x8 aq[2][2];
    #pragma unroll
    for (int rf = 0; rf < 2; ++rf)
        #pragma unroll
        for (int ks = 0; ks < 2; ++ks)
            aq[rf][ks] = *(const bf16x8*)(qb + bS512 + (size_t)(qw + rf * 16 + l15) * 512
                                          + hoff + ks * 32 + kgrp * 8);

    f32x4 O[2][4];
    float m[2][4], l[2][4];
    #pragma unroll
    for (int rf = 0; rf < 2; ++rf) {
        #pragma unroll
        for (int df = 0; df < 4; ++df) O[rf][df] = (f32x4){0.f, 0.f, 0.f, 0.f};
        #pragma unroll
        for (int j = 0; j < 4; ++j) { m[rf][j] = -3.0e38f; l[rf][j] = 0.f; }
    }

    const bf16_t* kbase = kb + bS512 + hoff;
    const bf16_t* vbase = vtb + ((size_t)b * 512 + hoff) * 1024;

    for (int kt = w; kt < ntiles; kt += 4) {
        const int kt0 = kt * 64;

        // ---- QK^T (Q pre-scaled) ----
        f32x4 S[2][4];
        #pragma unroll
        for (int rf = 0; rf < 2; ++rf)
            #pragma unroll
            for (int cf = 0; cf < 4; ++cf) S[rf][cf] = (f32x4){0.f, 0.f, 0.f, 0.f};

        __builtin_amdgcn_s_setprio(1);
        #pragma unroll
        for (int cf = 0; cf < 4; ++cf) {
            const bf16_t* krow = kbase + (size_t)(kt0 + cf * 16 + l15) * 512 + kgrp * 8;
            bf16x8 bk0 = *(const bf16x8*)krow;
            bf16x8 bk1 = *(const bf16x8*)(krow + 32);
            S[0][cf] = mfma16x16x32(aq[0][0], bk0, S[0][cf]);
            S[0][cf] = mfma16x16x32(aq[0][1], bk1, S[0][cf]);
            S[1][cf] = mfma16x16x32(aq[1][0], bk0, S[1][cf]);
            S[1][cf] = mfma16x16x32(aq[1][1], bk1, S[1][cf]);
        }
        __builtin_amdgcn_s_setprio(0);

        // ---- masks (exp2 domain, exact ties) + per-lane max ----
        float kmadd[4];
        #pragma unroll
        for (int cf = 0; cf < 4; ++cf)
            kmadd[cf] = (km[kt0 + cf * 16 + l15] == 0) ? CPOW : 0.0f;

        const bool needC = (kt0 + 63 > qw);
        float mx[2][4];
        #pragma unroll
        for (int rf = 0; rf < 2; ++rf)
            #pragma unroll
            for (int j = 0; j < 4; ++j) {
                const int qrow = qw + rf * 16 + kgrp * 4 + j;
                float mj = -3.0e38f;
                #pragma unroll
                for (int cf = 0; cf < 4; ++cf) {
                    float sub = kmadd[cf];
                    if (needC && (kt0 + cf * 16 + l15 > qrow)) sub += CPOW;
                    float s = S[rf][cf][j] - sub;
                    S[rf][cf][j] = s;
                    mj = fmaxf(mj, s);
                }
                mx[rf][j] = mj;
            }
        #pragma unroll
        for (int off = 1; off < 16; off <<= 1)
            #pragma unroll
            for (int rf = 0; rf < 2; ++rf)
                #pragma unroll
                for (int j = 0; j < 4; ++j)
                    mx[rf][j] = fmaxf(mx[rf][j], __shfl_xor(mx[rf][j], off));

        // ---- online update (l kept per-lane partial) ----
        float fac[2][4];
        #pragma unroll
        for (int rf = 0; rf < 2; ++rf)
            #pragma unroll
            for (int j = 0; j < 4; ++j) {
                float mn = fmaxf(m[rf][j], mx[rf][j]);
                fac[rf][j] = __builtin_amdgcn_exp2f(m[rf][j] - mn);
                m[rf][j] = mn;
            }
        #pragma unroll
        for (int rf = 0; rf < 2; ++rf)
            #pragma unroll
            for (int j = 0; j < 4; ++j) {
                float ps = 0.f;
                #pragma unroll
                for (int cf = 0; cf < 4; ++cf) {
                    float p = __builtin_amdgcn_exp2f(S[rf][cf][j] - m[rf][j]);
                    S[rf][cf][j] = p;
                    ps += p;
                }
                l[rf][j] = l[rf][j] * fac[rf][j] + ps;
            }
        #pragma unroll
        for (int rf = 0; rf < 2; ++rf)
            #pragma unroll
            for (int df = 0; df < 4; ++df)
                #pragma unroll
                for (int j = 0; j < 4; ++j)
                    O[rf][df][j] *= fac[rf][j];

        // ---- P -> per-wave LDS tile, wave-local wait ----
        #pragma unroll
        for (int rf = 0; rf < 2; ++rf)
            #pragma unroll
            for (int cf = 0; cf < 4; ++cf)
                #pragma unroll
                for (int j = 0; j < 4; ++j)
                    P[w][rf * 16 + kgrp * 4 + j][cf * 16 + l15] = (bf16_t)S[rf][cf][j];
        asm volatile("s_waitcnt lgkmcnt(0)" ::: "memory");

        bf16x8 pa[2][2];
        #pragma unroll
        for (int rf = 0; rf < 2; ++rf)
            #pragma unroll
            for (int ks = 0; ks < 2; ++ks)
                pa[rf][ks] = *(const bf16x8*)&P[w][rf * 16 + l15][ks * 32 + kgrp * 8];

        // ---- PV ----
        __builtin_amdgcn_s_setprio(1);
        #pragma unroll
        for (int df = 0; df < 4; ++df) {
            const bf16_t* vrow = vbase + (size_t)(df * 16 + l15) * 1024 + kt0 + kgrp * 8;
            bf16x8 vf0 = *(const bf16x8*)vrow;
            bf16x8 vf1 = *(const bf16x8*)(vrow + 32);
            O[0][df] = mfma16x16x32(pa[0][0], vf0, O[0][df]);
            O[0][df] = mfma16x16x32(pa[0][1], vf1, O[0][df]);
            O[1][df] = mfma16x16x32(pa[1][0], vf0, O[1][df]);
            O[1][df] = mfma16x16x32(pa[1][1], vf1, O[1][df]);
        }
        __builtin_amdgcn_s_setprio(0);
    }

    // ---- merge phase ----
    __syncthreads();   // all waves done with P region

    #pragma unroll
    for (int rf = 0; rf < 2; ++rf)
        #pragma unroll
        for (int j = 0; j < 4; ++j) {
            float lv = l[rf][j];
            #pragma unroll
            for (int off = 1; off < 16; off <<= 1) lv += __shfl_xor(lv, off);
            l[rf][j] = lv;
        }

    #pragma unroll
    for (int rf = 0; rf < 2; ++rf)
        #pragma unroll
        for (int df = 0; df < 4; ++df)
            #pragma unroll
            for (int j = 0; j < 4; ++j)
                Omg[w][rf * 16 + kgrp * 4 + j][df * 16 + l15] = (bf16_t)O[rf][df][j];
    if (l15 == 0) {
        #pragma unroll
        for (int rf = 0; rf < 2; ++rf)
            #pragma unroll
            for (int j = 0; j < 4; ++j) {
                mmg[w * 32 + rf * 16 + kgrp * 4 + j] = m[rf][j];
                lmg[w * 32 + rf * 16 + kgrp * 4 + j] = l[rf][j];
            }
    }
    __syncthreads();

    {
        const int r  = tid >> 3;        // 0..31
        const int c0 = (tid & 7) * 8;   // 0..56
        float m0 = mmg[r], m1 = mmg[32 + r], m2 = mmg[64 + r], m3 = mmg[96 + r];
        float M = fmaxf(fmaxf(m0, m1), fmaxf(m2, m3));
        float f0 = __builtin_amdgcn_exp2f(m0 - M), f1 = __builtin_amdgcn_exp2f(m1 - M);
        float f2 = __builtin_amdgcn_exp2f(m2 - M), f3 = __builtin_amdgcn_exp2f(m3 - M);
        float ls = lmg[r] * f0 + lmg[32 + r] * f1 + lmg[64 + r] * f2 + lmg[96 + r] * f3;
        float inv = 1.0f / ls;
        bf16x8 o0 = *(const bf16x8*)&Omg[0][r][c0];
        bf16x8 o1 = *(const bf16x8*)&Omg[1][r][c0];
        bf16x8 o2 = *(const bf16x8*)&Omg[2][r][c0];
        bf16x8 o3 = *(const bf16x8*)&Omg[3][r][c0];
        bf16_t outv[8];
        #pragma unroll
        for (int i = 0; i < 8; ++i) {
            float acc = (float)o0[i] * f0 + (float)o1[i] * f1
                      + (float)o2[i] * f2 + (float)o3[i] * f3;
            outv[i] = (bf16_t)(acc * inv);
        }
        *(bf16x8*)&attout[(size_t)(h * 1024 + qw + r) * 512 + b * 64 + c0] = *(bf16x8*)outv;
    }
}

// ---------------------------------------------------------------------------
extern "C" void kernel_launch(void* const* d_in, const int* in_sizes, int n_in,
                              void* d_out, int out_size, void* d_ws, size_t ws_size,
                              hipStream_t stream) {
    const float* query = (const float*)d_in[0];
    const float* key   = (const float*)d_in[1];
    const float* value = (const float*)d_in[2];
    const int*   qmask = (const int*)d_in[3];
    const int*   kmask = (const int*)d_in[4];
    const float* Wq    = (const float*)d_in[5];
    const float* Wk    = (const float*)d_in[6];
    const float* Wv    = (const float*)d_in[7];
    const float* Wo    = (const float*)d_in[8];
    float* out = (float*)d_out;

    const size_t NELEM = (size_t)8 * 1024 * 512;
    bf16_t* qb  = (bf16_t*)d_ws;
    bf16_t* kb  = qb + NELEM;
    bf16_t* vtb = kb + NELEM;   // [b][d(512)][s(1024)]
    bf16_t* ab  = vtb + NELEM;

    gemm_qkv<<<dim3(64, 4, 3), dim3(256), 0, stream>>>(query, key, value, Wq, Wk, Wv, qb, kb, vtb);
    attn_flash<<<dim3(64, 32), dim3(256), 0, stream>>>(qb, kb, vtb, kmask, ab);
    gemm_out<<<dim3(64, 4), dim3(256), 0, stream>>>(ab, Wo, out, qmask);
}

// Round 8
// 158.816 us; speedup vs baseline: 1.3940x; 1.0910x over previous
//
#include <hip/hip_runtime.h>
#include <hip/hip_bf16.h>

typedef __bf16 bf16_t;
typedef __bf16 bf16x8 __attribute__((ext_vector_type(8)));
typedef float f32x4 __attribute__((ext_vector_type(4)));

#define CPOW 1.4426950409e9f           // 1e9 * log2(e)  (masked scores round to exactly -CPOW/-2CPOW)
#define QSCALE 0.063758715f            // (1/sqrt(512)) * log2(e)
#define MSTAT 16.0f                    // static softmax max bound (exp2 domain; |s|<~15)

static __device__ __forceinline__ f32x4 mfma16x16x32(bf16x8 a, bf16x8 b, f32x4 c) {
    return __builtin_amdgcn_mfma_f32_16x16x32_bf16(a, b, c, 0, 0, 0);
}

// ---------------------------------------------------------------------------
// Fused QKV GEMM: for z in {0,1,2}: Out_z[8192,512] = A_z[8192,512] @ W_z[512,512]
// z==0 (Q): epilogue pre-scales by QSCALE (softmax exp2 domain).
// z<2: bf16 row-major out; z==2: bf16 transposed per-batch out[b][col][s] (V).
// ---------------------------------------------------------------------------
__global__ __launch_bounds__(256, 2) void gemm_qkv(
        const float* __restrict__ Aq, const float* __restrict__ Ak, const float* __restrict__ Av,
        const float* __restrict__ Wq, const float* __restrict__ Wk, const float* __restrict__ Wv,
        bf16_t* __restrict__ Oq, bf16_t* __restrict__ Ok, bf16_t* __restrict__ Ov) {
    __shared__ bf16_t As[128][40];
    __shared__ bf16_t Bs[128][40];

    const int tid  = threadIdx.x;
    const int lane = tid & 63;
    const int wave = tid >> 6;
    const int l15  = lane & 15;
    const int kgrp = lane >> 4;
    const int wr   = wave >> 1;
    const int wc   = wave & 1;

    const int row0 = blockIdx.x * 128;
    const int col0 = blockIdx.y * 128;
    const int z    = blockIdx.z;

    const float* A = (z == 0) ? Aq : (z == 1) ? Ak : Av;
    const float* W = (z == 0) ? Wq : (z == 1) ? Wk : Wv;

    const int ar  = tid >> 1;
    const int ach = (tid & 1) * 16;
    const int bc  = tid & 127;
    const int bkh = (tid >> 7) * 16;

    f32x4 acc[4][4];
    #pragma unroll
    for (int m = 0; m < 4; ++m)
        #pragma unroll
        for (int n = 0; n < 4; ++n) acc[m][n] = (f32x4){0.f, 0.f, 0.f, 0.f};

    float4 areg[4];
    float  breg[16];
    const float* Abase = A + (size_t)(row0 + ar) * 512 + ach;
    const float* Wbase = W + (size_t)bkh * 512 + col0 + bc;

    #pragma unroll
    for (int i = 0; i < 4; ++i) areg[i] = *(const float4*)(Abase + i * 4);
    #pragma unroll
    for (int i = 0; i < 16; ++i) breg[i] = Wbase[(size_t)i * 512];

    for (int kb0 = 0; kb0 < 512; kb0 += 32) {
        __syncthreads();
        {
            bf16x8 w0, w1;
            #pragma unroll
            for (int i = 0; i < 4; ++i) { w0[i] = (bf16_t)(&areg[0].x)[i]; w0[i + 4] = (bf16_t)(&areg[1].x)[i]; }
            #pragma unroll
            for (int i = 0; i < 4; ++i) { w1[i] = (bf16_t)(&areg[2].x)[i]; w1[i + 4] = (bf16_t)(&areg[3].x)[i]; }
            *(bf16x8*)&As[ar][ach]     = w0;
            *(bf16x8*)&As[ar][ach + 8] = w1;
            bf16x8 b0, b1;
            #pragma unroll
            for (int i = 0; i < 8; ++i) { b0[i] = (bf16_t)breg[i]; b1[i] = (bf16_t)breg[i + 8]; }
            *(bf16x8*)&Bs[bc][bkh]     = b0;
            *(bf16x8*)&Bs[bc][bkh + 8] = b1;
        }
        __syncthreads();
        if (kb0 + 32 < 512) {
            const float* An = Abase + kb0 + 32;
            #pragma unroll
            for (int i = 0; i < 4; ++i) areg[i] = *(const float4*)(An + i * 4);
            const float* Wn = Wbase + (size_t)(kb0 + 32) * 512;
            #pragma unroll
            for (int i = 0; i < 16; ++i) breg[i] = Wn[(size_t)i * 512];
        }
        bf16x8 af[4], bf[4];
        #pragma unroll
        for (int m = 0; m < 4; ++m) af[m] = *(const bf16x8*)&As[wr * 64 + m * 16 + l15][kgrp * 8];
        #pragma unroll
        for (int n = 0; n < 4; ++n) bf[n] = *(const bf16x8*)&Bs[wc * 64 + n * 16 + l15][kgrp * 8];
        __builtin_amdgcn_s_setprio(1);
        #pragma unroll
        for (int m = 0; m < 4; ++m)
            #pragma unroll
            for (int n = 0; n < 4; ++n)
                acc[m][n] = mfma16x16x32(af[m], bf[n], acc[m][n]);
        __builtin_amdgcn_s_setprio(0);
    }

    bf16_t* O = (z == 0) ? Oq : (z == 1) ? Ok : Ov;
    const float esc = (z == 0) ? QSCALE : 1.0f;
    #pragma unroll
    for (int m = 0; m < 4; ++m)
        #pragma unroll
        for (int j = 0; j < 4; ++j) {
            const int r = row0 + wr * 64 + m * 16 + kgrp * 4 + j;
            #pragma unroll
            for (int n = 0; n < 4; ++n) {
                const int c = col0 + wc * 64 + n * 16 + l15;
                if (z < 2) {
                    O[(size_t)r * 512 + c] = (bf16_t)(acc[m][n][j] * esc);
                } else {
                    const int bb = r >> 10, ss = r & 1023;
                    O[((size_t)bb * 512 + c) * 1024 + ss] = (bf16_t)acc[m][n][j];
                }
            }
        }
}

// ---------------------------------------------------------------------------
// Output GEMM: out[8192,512] = relu(ab @ Wo) * qmask[row],  f32 out.
// ---------------------------------------------------------------------------
__global__ __launch_bounds__(256, 2) void gemm_out(const bf16_t* __restrict__ Ab,
                                                   const float* __restrict__ W,
                                                   float* __restrict__ Out,
                                                   const int* __restrict__ qmask) {
    __shared__ bf16_t As[128][40];
    __shared__ bf16_t Bs[128][40];

    const int tid  = threadIdx.x;
    const int lane = tid & 63;
    const int wave = tid >> 6;
    const int l15  = lane & 15;
    const int kgrp = lane >> 4;
    const int wr   = wave >> 1;
    const int wc   = wave & 1;

    const int row0 = blockIdx.x * 128;
    const int col0 = blockIdx.y * 128;

    const int ar  = tid >> 1;
    const int ach = (tid & 1) * 16;
    const int bc  = tid & 127;
    const int bkh = (tid >> 7) * 16;

    f32x4 acc[4][4];
    #pragma unroll
    for (int m = 0; m < 4; ++m)
        #pragma unroll
        for (int n = 0; n < 4; ++n) acc[m][n] = (f32x4){0.f, 0.f, 0.f, 0.f};

    bf16x8 areg[2];
    float  breg[16];
    const bf16_t* Abase = Ab + (size_t)(row0 + ar) * 512 + ach;
    const float*  Wbase = W + (size_t)bkh * 512 + col0 + bc;

    areg[0] = *(const bf16x8*)Abase;
    areg[1] = *(const bf16x8*)(Abase + 8);
    #pragma unroll
    for (int i = 0; i < 16; ++i) breg[i] = Wbase[(size_t)i * 512];

    for (int kb0 = 0; kb0 < 512; kb0 += 32) {
        __syncthreads();
        *(bf16x8*)&As[ar][ach]     = areg[0];
        *(bf16x8*)&As[ar][ach + 8] = areg[1];
        {
            bf16x8 b0, b1;
            #pragma unroll
            for (int i = 0; i < 8; ++i) { b0[i] = (bf16_t)breg[i]; b1[i] = (bf16_t)breg[i + 8]; }
            *(bf16x8*)&Bs[bc][bkh]     = b0;
            *(bf16x8*)&Bs[bc][bkh + 8] = b1;
        }
        __syncthreads();
        if (kb0 + 32 < 512) {
            const bf16_t* An = Abase + kb0 + 32;
            areg[0] = *(const bf16x8*)An;
            areg[1] = *(const bf16x8*)(An + 8);
            const float* Wn = Wbase + (size_t)(kb0 + 32) * 512;
            #pragma unroll
            for (int i = 0; i < 16; ++i) breg[i] = Wn[(size_t)i * 512];
        }
        bf16x8 af[4], bf[4];
        #pragma unroll
        for (int m = 0; m < 4; ++m) af[m] = *(const bf16x8*)&As[wr * 64 + m * 16 + l15][kgrp * 8];
        #pragma unroll
        for (int n = 0; n < 4; ++n) bf[n] = *(const bf16x8*)&Bs[wc * 64 + n * 16 + l15][kgrp * 8];
        __builtin_amdgcn_s_setprio(1);
        #pragma unroll
        for (int m = 0; m < 4; ++m)
            #pragma unroll
            for (int n = 0; n < 4; ++n)
                acc[m][n] = mfma16x16x32(af[m], bf[n], acc[m][n]);
        __builtin_amdgcn_s_setprio(0);
    }

    #pragma unroll
    for (int m = 0; m < 4; ++m)
        #pragma unroll
        for (int j = 0; j < 4; ++j) {
            const int r = row0 + wr * 64 + m * 16 + kgrp * 4 + j;
            const float fq = (float)qmask[r];
            #pragma unroll
            for (int n = 0; n < 4; ++n) {
                const int c = col0 + wc * 64 + n * 16 + l15;
                Out[(size_t)r * 512 + c] = fmaxf(acc[m][n][j], 0.0f) * fq;
            }
        }
}

// ---------------------------------------------------------------------------
// Flash attention, split-K across 4 waves, 32 q-rows/block.
// FAST path (qw >= first1): static-max softmax p = exp2(s - MSTAT): no max
//   shuffles, no rescale (math-identical to true softmax; masked -> exact 0).
// SLOW path (qw < first1, ~1 block/hb): online true max over all 16 tiles
//   (exact -1e9 tie semantics, matching the reference's uniform tie rows).
// Merge: per-wave (m,l,O) -> exact softmax merge (fast waves store m=MSTAT).
// __launch_bounds__(256,4): cap 128 >> natural ~80 -> NO SPILL (R6/R7 lesson:
// min-waves 5/6 squeezed regalloc into arch/acc split + scratch spills).
// grid = (64 hb, 32): id%8 = b -> per-XCD batch locality; heavy chunks first.
// ---------------------------------------------------------------------------
__global__ __launch_bounds__(256, 4) void attn_flash(const bf16_t* __restrict__ qb,
                                                     const bf16_t* __restrict__ kb,
                                                     const bf16_t* __restrict__ vtb,
                                                     const int* __restrict__ key_mask,
                                                     bf16_t* __restrict__ attout) {
    __shared__ char shbuf[19456];
    bf16_t (*P)[32][72]   = (bf16_t(*)[32][72])shbuf;   // per-wave P tiles (18432 B)
    bf16_t (*Omg)[32][72] = (bf16_t(*)[32][72])shbuf;   // merge O (aliases P, after barrier)
    float* mmg = (float*)(shbuf + 18432);               // 4*32 floats
    float* lmg = (float*)(shbuf + 18432 + 512);         // 4*32 floats

    const int tid  = threadIdx.x;
    const int lane = tid & 63;
    const int w    = tid >> 6;     // wave id = K-slice
    const int l15  = lane & 15;
    const int kgrp = lane >> 4;

    const int hb = blockIdx.x;
    const int h  = hb >> 3;
    const int b  = hb & 7;
    const int qw = (31 - (int)blockIdx.y) * 32;

    const size_t bS512 = (size_t)b * 1024 * 512;
    const int hoff = h * 64;
    const int* km = key_mask + h * 1024;

    int kmv = km[lane];
    unsigned long long bal = __ballot(kmv != 0);
    int first1 = bal ? (__ffsll(bal) - 1) : 64;
    const bool slow = (qw < first1);
    const int ntiles = slow ? 16 : ((qw + 95) >> 6);

    bf16x8 aq[2][2];
    #pragma unroll
    for (int rf = 0; rf < 2; ++rf)
        #pragma unroll
        for (int ks = 0; ks < 2; ++ks)
            aq[rf][ks] = *(const bf16x8*)(qb + bS512 + (size_t)(qw + rf * 16 + l15) * 512
                                          + hoff + ks * 32 + kgrp * 8);

    f32x4 O[2][4];
    float m[2][4], l[2][4];
    #pragma unroll
    for (int rf = 0; rf < 2; ++rf) {
        #pragma unroll
        for (int df = 0; df < 4; ++df) O[rf][df] = (f32x4){0.f, 0.f, 0.f, 0.f};
        #pragma unroll
        for (int j = 0; j < 4; ++j) { m[rf][j] = slow ? -3.0e38f : MSTAT; l[rf][j] = 0.f; }
    }

    const bf16_t* kbase = kb + bS512 + hoff;
    const bf16_t* vbase = vtb + ((size_t)b * 512 + hoff) * 1024;

    for (int kt = w; kt < ntiles; kt += 4) {
        const int kt0 = kt * 64;

        // ---- QK^T (Q pre-scaled to exp2 domain) ----
        f32x4 S[2][4];
        #pragma unroll
        for (int rf = 0; rf < 2; ++rf)
            #pragma unroll
            for (int cf = 0; cf < 4; ++cf) S[rf][cf] = (f32x4){0.f, 0.f, 0.f, 0.f};

        __builtin_amdgcn_s_setprio(1);
        #pragma unroll
        for (int cf = 0; cf < 4; ++cf) {
            const bf16_t* krow = kbase + (size_t)(kt0 + cf * 16 + l15) * 512 + kgrp * 8;
            bf16x8 bk0 = *(const bf16x8*)krow;
            bf16x8 bk1 = *(const bf16x8*)(krow + 32);
            S[0][cf] = mfma16x16x32(aq[0][0], bk0, S[0][cf]);
            S[0][cf] = mfma16x16x32(aq[0][1], bk1, S[0][cf]);
            S[1][cf] = mfma16x16x32(aq[1][0], bk0, S[1][cf]);
            S[1][cf] = mfma16x16x32(aq[1][1], bk1, S[1][cf]);
        }
        __builtin_amdgcn_s_setprio(0);

        float kmadd[4];
        #pragma unroll
        for (int cf = 0; cf < 4; ++cf)
            kmadd[cf] = (km[kt0 + cf * 16 + l15] == 0) ? CPOW : 0.0f;

        const bool needC = (kt0 + 63 > qw);

        if (!slow) {
            // ---- FAST: static max. p = exp2(S - sub - MSTAT); l += sum ----
            #pragma unroll
            for (int rf = 0; rf < 2; ++rf)
                #pragma unroll
                for (int j = 0; j < 4; ++j) {
                    const int qrow = qw + rf * 16 + kgrp * 4 + j;
                    float ps = 0.f;
                    #pragma unroll
                    for (int cf = 0; cf < 4; ++cf) {
                        float sub = kmadd[cf] + MSTAT;
                        if (needC && (kt0 + cf * 16 + l15 > qrow)) sub += CPOW;
                        float p = __builtin_amdgcn_exp2f(S[rf][cf][j] - sub);
                        S[rf][cf][j] = p;
                        ps += p;
                    }
                    l[rf][j] += ps;
                }
        } else {
            // ---- SLOW: exact online max (tie rows; exact -CPOW ties) ----
            float mx[2][4];
            #pragma unroll
            for (int rf = 0; rf < 2; ++rf)
                #pragma unroll
                for (int j = 0; j < 4; ++j) {
                    const int qrow = qw + rf * 16 + kgrp * 4 + j;
                    float mj = -3.0e38f;
                    #pragma unroll
                    for (int cf = 0; cf < 4; ++cf) {
                        float sub = kmadd[cf];
                        if (kt0 + cf * 16 + l15 > qrow) sub += CPOW;
                        float s = S[rf][cf][j] - sub;
                        S[rf][cf][j] = s;
                        mj = fmaxf(mj, s);
                    }
                    mx[rf][j] = mj;
                }
            #pragma unroll
            for (int off = 1; off < 16; off <<= 1)
                #pragma unroll
                for (int rf = 0; rf < 2; ++rf)
                    #pragma unroll
                    for (int j = 0; j < 4; ++j)
                        mx[rf][j] = fmaxf(mx[rf][j], __shfl_xor(mx[rf][j], off));

            float fac[2][4];
            #pragma unroll
            for (int rf = 0; rf < 2; ++rf)
                #pragma unroll
                for (int j = 0; j < 4; ++j) {
                    float mn = fmaxf(m[rf][j], mx[rf][j]);
                    fac[rf][j] = __builtin_amdgcn_exp2f(m[rf][j] - mn);
                    m[rf][j] = mn;
                }
            #pragma unroll
            for (int rf = 0; rf < 2; ++rf)
                #pragma unroll
                for (int j = 0; j < 4; ++j) {
                    float ps = 0.f;
                    #pragma unroll
                    for (int cf = 0; cf < 4; ++cf) {
                        float p = __builtin_amdgcn_exp2f(S[rf][cf][j] - m[rf][j]);
                        S[rf][cf][j] = p;
                        ps += p;
                    }
                    l[rf][j] = l[rf][j] * fac[rf][j] + ps;
                }
            #pragma unroll
            for (int rf = 0; rf < 2; ++rf)
                #pragma unroll
                for (int df = 0; df < 4; ++df)
                    #pragma unroll
                    for (int j = 0; j < 4; ++j)
                        O[rf][df][j] *= fac[rf][j];
        }

        // ---- P -> per-wave LDS tile, wave-local wait ----
        #pragma unroll
        for (int rf = 0; rf < 2; ++rf)
            #pragma unroll
            for (int cf = 0; cf < 4; ++cf)
                #pragma unroll
                for (int j = 0; j < 4; ++j)
                    P[w][rf * 16 + kgrp * 4 + j][cf * 16 + l15] = (bf16_t)S[rf][cf][j];
        asm volatile("s_waitcnt lgkmcnt(0)" ::: "memory");

        bf16x8 pa[2][2];
        #pragma unroll
        for (int rf = 0; rf < 2; ++rf)
            #pragma unroll
            for (int ks = 0; ks < 2; ++ks)
                pa[rf][ks] = *(const bf16x8*)&P[w][rf * 16 + l15][ks * 32 + kgrp * 8];

        // ---- PV ----
        __builtin_amdgcn_s_setprio(1);
        #pragma unroll
        for (int df = 0; df < 4; ++df) {
            const bf16_t* vrow = vbase + (size_t)(df * 16 + l15) * 1024 + kt0 + kgrp * 8;
            bf16x8 vf0 = *(const bf16x8*)vrow;
            bf16x8 vf1 = *(const bf16x8*)(vrow + 32);
            O[0][df] = mfma16x16x32(pa[0][0], vf0, O[0][df]);
            O[0][df] = mfma16x16x32(pa[0][1], vf1, O[0][df]);
            O[1][df] = mfma16x16x32(pa[1][0], vf0, O[1][df]);
            O[1][df] = mfma16x16x32(pa[1][1], vf1, O[1][df]);
        }
        __builtin_amdgcn_s_setprio(0);
    }

    // ---- merge phase ----
    __syncthreads();   // all waves done with P region

    #pragma unroll
    for (int rf = 0; rf < 2; ++rf)
        #pragma unroll
        for (int j = 0; j < 4; ++j) {
            float lv = l[rf][j];
            #pragma unroll
            for (int off = 1; off < 16; off <<= 1) lv += __shfl_xor(lv, off);
            l[rf][j] = lv;
        }

    #pragma unroll
    for (int rf = 0; rf < 2; ++rf)
        #pragma unroll
        for (int df = 0; df < 4; ++df)
            #pragma unroll
            for (int j = 0; j < 4; ++j)
                Omg[w][rf * 16 + kgrp * 4 + j][df * 16 + l15] = (bf16_t)O[rf][df][j];
    if (l15 == 0) {
        #pragma unroll
        for (int rf = 0; rf < 2; ++rf)
            #pragma unroll
            for (int j = 0; j < 4; ++j) {
                mmg[w * 32 + rf * 16 + kgrp * 4 + j] = m[rf][j];
                lmg[w * 32 + rf * 16 + kgrp * 4 + j] = l[rf][j];
            }
    }
    __syncthreads();

    {
        const int r  = tid >> 3;        // 0..31
        const int c0 = (tid & 7) * 8;   // 0..56
        float m0 = mmg[r], m1 = mmg[32 + r], m2 = mmg[64 + r], m3 = mmg[96 + r];
        float M = fmaxf(fmaxf(m0, m1), fmaxf(m2, m3));
        float f0 = __builtin_amdgcn_exp2f(m0 - M), f1 = __builtin_amdgcn_exp2f(m1 - M);
        float f2 = __builtin_amdgcn_exp2f(m2 - M), f3 = __builtin_amdgcn_exp2f(m3 - M);
        float ls = lmg[r] * f0 + lmg[32 + r] * f1 + lmg[64 + r] * f2 + lmg[96 + r] * f3;
        float inv = 1.0f / ls;
        bf16x8 o0 = *(const bf16x8*)&Omg[0][r][c0];
        bf16x8 o1 = *(const bf16x8*)&Omg[1][r][c0];
        bf16x8 o2 = *(const bf16x8*)&Omg[2][r][c0];
        bf16x8 o3 = *(const bf16x8*)&Omg[3][r][c0];
        bf16_t outv[8];
        #pragma unroll
        for (int i = 0; i < 8; ++i) {
            float acc = (float)o0[i] * f0 + (float)o1[i] * f1
                      + (float)o2[i] * f2 + (float)o3[i] * f3;
            outv[i] = (bf16_t)(acc * inv);
        }
        *(bf16x8*)&attout[(size_t)(h * 1024 + qw + r) * 512 + b * 64 + c0] = *(bf16x8*)outv;
    }
}

// ---------------------------------------------------------------------------
extern "C" void kernel_launch(void* const* d_in, const int* in_sizes, int n_in,
                              void* d_out, int out_size, void* d_ws, size_t ws_size,
                              hipStream_t stream) {
    const float* query = (const float*)d_in[0];
    const float* key   = (const float*)d_in[1];
    const float* value = (const float*)d_in[2];
    const int*   qmask = (const int*)d_in[3];
    const int*   kmask = (const int*)d_in[4];
    const float* Wq    = (const float*)d_in[5];
    const float* Wk    = (const float*)d_in[6];
    const float* Wv    = (const float*)d_in[7];
    const float* Wo    = (const float*)d_in[8];
    float* out = (float*)d_out;

    const size_t NELEM = (size_t)8 * 1024 * 512;
    bf16_t* qb  = (bf16_t*)d_ws;
    bf16_t* kb  = qb + NELEM;
    bf16_t* vtb = kb + NELEM;   // [b][d(512)][s(1024)]
    bf16_t* ab  = vtb + NELEM;

    gemm_qkv<<<dim3(64, 4, 3), dim3(256), 0, stream>>>(query, key, value, Wq, Wk, Wv, qb, kb, vtb);
    attn_flash<<<dim3(64, 32), dim3(256), 0, stream>>>(qb, kb, vtb, kmask, ab);
    gemm_out<<<dim3(64, 4), dim3(256), 0, stream>>>(ab, Wo, out, qmask);
}

// Round 9
// 114.938 us; speedup vs baseline: 1.9261x; 1.3818x over previous
//
#include <hip/hip_runtime.h>
#include <hip/hip_bf16.h>

typedef __bf16 bf16_t;
typedef __bf16 bf16x8 __attribute__((ext_vector_type(8)));
typedef float f32x4 __attribute__((ext_vector_type(4)));

#define CPOW 1.4426950409e9f           // 1e9 * log2(e)  (masked scores round to exactly -CPOW/-2CPOW)
#define QSCALE 0.063758715f            // (1/sqrt(512)) * log2(e)
#define MSTAT 16.0f                    // static softmax max bound (exp2 domain; |s|<~15)

static __device__ __forceinline__ f32x4 mfma16x16x32(bf16x8 a, bf16x8 b, f32x4 c) {
    return __builtin_amdgcn_mfma_f32_16x16x32_bf16(a, b, c, 0, 0, 0);
}

// ---------------------------------------------------------------------------
// Fused QKV GEMM: for z in {0,1,2}: Out_z[8192,512] = A_z[8192,512] @ W_z[512,512]
// z==0 (Q): epilogue pre-scales by QSCALE (softmax exp2 domain).
// z<2: bf16 row-major out; z==2: bf16 transposed per-batch out[b][col][s] (V).
// ---------------------------------------------------------------------------
__global__ __launch_bounds__(256, 2) void gemm_qkv(
        const float* __restrict__ Aq, const float* __restrict__ Ak, const float* __restrict__ Av,
        const float* __restrict__ Wq, const float* __restrict__ Wk, const float* __restrict__ Wv,
        bf16_t* __restrict__ Oq, bf16_t* __restrict__ Ok, bf16_t* __restrict__ Ov) {
    __shared__ bf16_t As[128][40];
    __shared__ bf16_t Bs[128][40];

    const int tid  = threadIdx.x;
    const int lane = tid & 63;
    const int wave = tid >> 6;
    const int l15  = lane & 15;
    const int kgrp = lane >> 4;
    const int wr   = wave >> 1;
    const int wc   = wave & 1;

    const int row0 = blockIdx.x * 128;
    const int col0 = blockIdx.y * 128;
    const int z    = blockIdx.z;

    const float* A = (z == 0) ? Aq : (z == 1) ? Ak : Av;
    const float* W = (z == 0) ? Wq : (z == 1) ? Wk : Wv;

    const int ar  = tid >> 1;
    const int ach = (tid & 1) * 16;
    const int bc  = tid & 127;
    const int bkh = (tid >> 7) * 16;

    f32x4 acc[4][4];
    #pragma unroll
    for (int m = 0; m < 4; ++m)
        #pragma unroll
        for (int n = 0; n < 4; ++n) acc[m][n] = (f32x4){0.f, 0.f, 0.f, 0.f};

    float4 areg[4];
    float  breg[16];
    const float* Abase = A + (size_t)(row0 + ar) * 512 + ach;
    const float* Wbase = W + (size_t)bkh * 512 + col0 + bc;

    #pragma unroll
    for (int i = 0; i < 4; ++i) areg[i] = *(const float4*)(Abase + i * 4);
    #pragma unroll
    for (int i = 0; i < 16; ++i) breg[i] = Wbase[(size_t)i * 512];

    for (int kb0 = 0; kb0 < 512; kb0 += 32) {
        __syncthreads();
        {
            bf16x8 w0, w1;
            #pragma unroll
            for (int i = 0; i < 4; ++i) { w0[i] = (bf16_t)(&areg[0].x)[i]; w0[i + 4] = (bf16_t)(&areg[1].x)[i]; }
            #pragma unroll
            for (int i = 0; i < 4; ++i) { w1[i] = (bf16_t)(&areg[2].x)[i]; w1[i + 4] = (bf16_t)(&areg[3].x)[i]; }
            *(bf16x8*)&As[ar][ach]     = w0;
            *(bf16x8*)&As[ar][ach + 8] = w1;
            bf16x8 b0, b1;
            #pragma unroll
            for (int i = 0; i < 8; ++i) { b0[i] = (bf16_t)breg[i]; b1[i] = (bf16_t)breg[i + 8]; }
            *(bf16x8*)&Bs[bc][bkh]     = b0;
            *(bf16x8*)&Bs[bc][bkh + 8] = b1;
        }
        __syncthreads();
        if (kb0 + 32 < 512) {
            const float* An = Abase + kb0 + 32;
            #pragma unroll
            for (int i = 0; i < 4; ++i) areg[i] = *(const float4*)(An + i * 4);
            const float* Wn = Wbase + (size_t)(kb0 + 32) * 512;
            #pragma unroll
            for (int i = 0; i < 16; ++i) breg[i] = Wn[(size_t)i * 512];
        }
        bf16x8 af[4], bf[4];
        #pragma unroll
        for (int m = 0; m < 4; ++m) af[m] = *(const bf16x8*)&As[wr * 64 + m * 16 + l15][kgrp * 8];
        #pragma unroll
        for (int n = 0; n < 4; ++n) bf[n] = *(const bf16x8*)&Bs[wc * 64 + n * 16 + l15][kgrp * 8];
        __builtin_amdgcn_s_setprio(1);
        #pragma unroll
        for (int m = 0; m < 4; ++m)
            #pragma unroll
            for (int n = 0; n < 4; ++n)
                acc[m][n] = mfma16x16x32(af[m], bf[n], acc[m][n]);
        __builtin_amdgcn_s_setprio(0);
    }

    bf16_t* O = (z == 0) ? Oq : (z == 1) ? Ok : Ov;
    const float esc = (z == 0) ? QSCALE : 1.0f;
    #pragma unroll
    for (int m = 0; m < 4; ++m)
        #pragma unroll
        for (int j = 0; j < 4; ++j) {
            const int r = row0 + wr * 64 + m * 16 + kgrp * 4 + j;
            #pragma unroll
            for (int n = 0; n < 4; ++n) {
                const int c = col0 + wc * 64 + n * 16 + l15;
                if (z < 2) {
                    O[(size_t)r * 512 + c] = (bf16_t)(acc[m][n][j] * esc);
                } else {
                    const int bb = r >> 10, ss = r & 1023;
                    O[((size_t)bb * 512 + c) * 1024 + ss] = (bf16_t)acc[m][n][j];
                }
            }
        }
}

// ---------------------------------------------------------------------------
// Output GEMM: out[8192,512] = relu(ab @ Wo) * qmask[row],  f32 out.
// ---------------------------------------------------------------------------
__global__ __launch_bounds__(256, 2) void gemm_out(const bf16_t* __restrict__ Ab,
                                                   const float* __restrict__ W,
                                                   float* __restrict__ Out,
                                                   const int* __restrict__ qmask) {
    __shared__ bf16_t As[128][40];
    __shared__ bf16_t Bs[128][40];

    const int tid  = threadIdx.x;
    const int lane = tid & 63;
    const int wave = tid >> 6;
    const int l15  = lane & 15;
    const int kgrp = lane >> 4;
    const int wr   = wave >> 1;
    const int wc   = wave & 1;

    const int row0 = blockIdx.x * 128;
    const int col0 = blockIdx.y * 128;

    const int ar  = tid >> 1;
    const int ach = (tid & 1) * 16;
    const int bc  = tid & 127;
    const int bkh = (tid >> 7) * 16;

    f32x4 acc[4][4];
    #pragma unroll
    for (int m = 0; m < 4; ++m)
        #pragma unroll
        for (int n = 0; n < 4; ++n) acc[m][n] = (f32x4){0.f, 0.f, 0.f, 0.f};

    bf16x8 areg[2];
    float  breg[16];
    const bf16_t* Abase = Ab + (size_t)(row0 + ar) * 512 + ach;
    const float*  Wbase = W + (size_t)bkh * 512 + col0 + bc;

    areg[0] = *(const bf16x8*)Abase;
    areg[1] = *(const bf16x8*)(Abase + 8);
    #pragma unroll
    for (int i = 0; i < 16; ++i) breg[i] = Wbase[(size_t)i * 512];

    for (int kb0 = 0; kb0 < 512; kb0 += 32) {
        __syncthreads();
        *(bf16x8*)&As[ar][ach]     = areg[0];
        *(bf16x8*)&As[ar][ach + 8] = areg[1];
        {
            bf16x8 b0, b1;
            #pragma unroll
            for (int i = 0; i < 8; ++i) { b0[i] = (bf16_t)breg[i]; b1[i] = (bf16_t)breg[i + 8]; }
            *(bf16x8*)&Bs[bc][bkh]     = b0;
            *(bf16x8*)&Bs[bc][bkh + 8] = b1;
        }
        __syncthreads();
        if (kb0 + 32 < 512) {
            const bf16_t* An = Abase + kb0 + 32;
            areg[0] = *(const bf16x8*)An;
            areg[1] = *(const bf16x8*)(An + 8);
            const float* Wn = Wbase + (size_t)(kb0 + 32) * 512;
            #pragma unroll
            for (int i = 0; i < 16; ++i) breg[i] = Wn[(size_t)i * 512];
        }
        bf16x8 af[4], bf[4];
        #pragma unroll
        for (int m = 0; m < 4; ++m) af[m] = *(const bf16x8*)&As[wr * 64 + m * 16 + l15][kgrp * 8];
        #pragma unroll
        for (int n = 0; n < 4; ++n) bf[n] = *(const bf16x8*)&Bs[wc * 64 + n * 16 + l15][kgrp * 8];
        __builtin_amdgcn_s_setprio(1);
        #pragma unroll
        for (int m = 0; m < 4; ++m)
            #pragma unroll
            for (int n = 0; n < 4; ++n)
                acc[m][n] = mfma16x16x32(af[m], bf[n], acc[m][n]);
        __builtin_amdgcn_s_setprio(0);
    }

    #pragma unroll
    for (int m = 0; m < 4; ++m)
        #pragma unroll
        for (int j = 0; j < 4; ++j) {
            const int r = row0 + wr * 64 + m * 16 + kgrp * 4 + j;
            const float fq = (float)qmask[r];
            #pragma unroll
            for (int n = 0; n < 4; ++n) {
                const int c = col0 + wc * 64 + n * 16 + l15;
                Out[(size_t)r * 512 + c] = fmaxf(acc[m][n][j], 0.0f) * fq;
            }
        }
}

// ---------------------------------------------------------------------------
// Flash attention, split-K across 4 waves, 32 q-rows/block.
// FAST path (qw >= first1): static-max softmax p = exp2(s - MSTAT): no max
//   shuffles, no rescale (math-identical to true softmax; masked -> exact 0).
// SLOW path (qw < first1, ~1 block/hb): online true max over all 16 tiles
//   (exact -1e9 tie semantics, matching the reference's uniform tie rows).
// Merge: per-wave (m,l,O) -> exact softmax merge (fast waves store m=MSTAT).
// __launch_bounds__(256,3): cap 170 — the ONLY no-spill regime measured.
// gfx950 unified VGPR/AGPR file: kernel's natural arch+acc total is ~130-150;
// caps of 85/102/128 (min-waves 6/5/4) all forced arch/acc splits that spilled
// the hot loop to scratch (R6: FETCH 255MB, R7: WRITE 253MB, R8: 135/158MB).
// Occupancy must come from less state, never from a register cap.
// grid = (64 hb, 32): id%8 = b -> per-XCD batch locality; heavy chunks first.
// ---------------------------------------------------------------------------
__global__ __launch_bounds__(256, 3) void attn_flash(const bf16_t* __restrict__ qb,
                                                     const bf16_t* __restrict__ kb,
                                                     const bf16_t* __restrict__ vtb,
                                                     const int* __restrict__ key_mask,
                                                     bf16_t* __restrict__ attout) {
    __shared__ char shbuf[19456];
    bf16_t (*P)[32][72]   = (bf16_t(*)[32][72])shbuf;   // per-wave P tiles (18432 B)
    bf16_t (*Omg)[32][72] = (bf16_t(*)[32][72])shbuf;   // merge O (aliases P, after barrier)
    float* mmg = (float*)(shbuf + 18432);               // 4*32 floats
    float* lmg = (float*)(shbuf + 18432 + 512);         // 4*32 floats

    const int tid  = threadIdx.x;
    const int lane = tid & 63;
    const int w    = tid >> 6;     // wave id = K-slice
    const int l15  = lane & 15;
    const int kgrp = lane >> 4;

    const int hb = blockIdx.x;
    const int h  = hb >> 3;
    const int b  = hb & 7;
    const int qw = (31 - (int)blockIdx.y) * 32;

    const size_t bS512 = (size_t)b * 1024 * 512;
    const int hoff = h * 64;
    const int* km = key_mask + h * 1024;

    int kmv = km[lane];
    unsigned long long bal = __ballot(kmv != 0);
    int first1 = bal ? (__ffsll(bal) - 1) : 64;
    const bool slow = (qw < first1);
    const int ntiles = slow ? 16 : ((qw + 95) >> 6);

    bf16x8 aq[2][2];
    #pragma unroll
    for (int rf = 0; rf < 2; ++rf)
        #pragma unroll
        for (int ks = 0; ks < 2; ++ks)
            aq[rf][ks] = *(const bf16x8*)(qb + bS512 + (size_t)(qw + rf * 16 + l15) * 512
                                          + hoff + ks * 32 + kgrp * 8);

    f32x4 O[2][4];
    float m[2][4], l[2][4];
    #pragma unroll
    for (int rf = 0; rf < 2; ++rf) {
        #pragma unroll
        for (int df = 0; df < 4; ++df) O[rf][df] = (f32x4){0.f, 0.f, 0.f, 0.f};
        #pragma unroll
        for (int j = 0; j < 4; ++j) { m[rf][j] = slow ? -3.0e38f : MSTAT; l[rf][j] = 0.f; }
    }

    const bf16_t* kbase = kb + bS512 + hoff;
    const bf16_t* vbase = vtb + ((size_t)b * 512 + hoff) * 1024;

    for (int kt = w; kt < ntiles; kt += 4) {
        const int kt0 = kt * 64;

        // ---- QK^T (Q pre-scaled to exp2 domain) ----
        f32x4 S[2][4];
        #pragma unroll
        for (int rf = 0; rf < 2; ++rf)
            #pragma unroll
            for (int cf = 0; cf < 4; ++cf) S[rf][cf] = (f32x4){0.f, 0.f, 0.f, 0.f};

        __builtin_amdgcn_s_setprio(1);
        #pragma unroll
        for (int cf = 0; cf < 4; ++cf) {
            const bf16_t* krow = kbase + (size_t)(kt0 + cf * 16 + l15) * 512 + kgrp * 8;
            bf16x8 bk0 = *(const bf16x8*)krow;
            bf16x8 bk1 = *(const bf16x8*)(krow + 32);
            S[0][cf] = mfma16x16x32(aq[0][0], bk0, S[0][cf]);
            S[0][cf] = mfma16x16x32(aq[0][1], bk1, S[0][cf]);
            S[1][cf] = mfma16x16x32(aq[1][0], bk0, S[1][cf]);
            S[1][cf] = mfma16x16x32(aq[1][1], bk1, S[1][cf]);
        }
        __builtin_amdgcn_s_setprio(0);

        float kmadd[4];
        #pragma unroll
        for (int cf = 0; cf < 4; ++cf)
            kmadd[cf] = (km[kt0 + cf * 16 + l15] == 0) ? CPOW : 0.0f;

        const bool needC = (kt0 + 63 > qw);

        if (!slow) {
            // ---- FAST: static max. p = exp2(S - sub - MSTAT); l += sum ----
            #pragma unroll
            for (int rf = 0; rf < 2; ++rf)
                #pragma unroll
                for (int j = 0; j < 4; ++j) {
                    const int qrow = qw + rf * 16 + kgrp * 4 + j;
                    float ps = 0.f;
                    #pragma unroll
                    for (int cf = 0; cf < 4; ++cf) {
                        float sub = kmadd[cf] + MSTAT;
                        if (needC && (kt0 + cf * 16 + l15 > qrow)) sub += CPOW;
                        float p = __builtin_amdgcn_exp2f(S[rf][cf][j] - sub);
                        S[rf][cf][j] = p;
                        ps += p;
                    }
                    l[rf][j] += ps;
                }
        } else {
            // ---- SLOW: exact online max (tie rows; exact -CPOW ties) ----
            float mx[2][4];
            #pragma unroll
            for (int rf = 0; rf < 2; ++rf)
                #pragma unroll
                for (int j = 0; j < 4; ++j) {
                    const int qrow = qw + rf * 16 + kgrp * 4 + j;
                    float mj = -3.0e38f;
                    #pragma unroll
                    for (int cf = 0; cf < 4; ++cf) {
                        float sub = kmadd[cf];
                        if (kt0 + cf * 16 + l15 > qrow) sub += CPOW;
                        float s = S[rf][cf][j] - sub;
                        S[rf][cf][j] = s;
                        mj = fmaxf(mj, s);
                    }
                    mx[rf][j] = mj;
                }
            #pragma unroll
            for (int off = 1; off < 16; off <<= 1)
                #pragma unroll
                for (int rf = 0; rf < 2; ++rf)
                    #pragma unroll
                    for (int j = 0; j < 4; ++j)
                        mx[rf][j] = fmaxf(mx[rf][j], __shfl_xor(mx[rf][j], off));

            float fac[2][4];
            #pragma unroll
            for (int rf = 0; rf < 2; ++rf)
                #pragma unroll
                for (int j = 0; j < 4; ++j) {
                    float mn = fmaxf(m[rf][j], mx[rf][j]);
                    fac[rf][j] = __builtin_amdgcn_exp2f(m[rf][j] - mn);
                    m[rf][j] = mn;
                }
            #pragma unroll
            for (int rf = 0; rf < 2; ++rf)
                #pragma unroll
                for (int j = 0; j < 4; ++j) {
                    float ps = 0.f;
                    #pragma unroll
                    for (int cf = 0; cf < 4; ++cf) {
                        float p = __builtin_amdgcn_exp2f(S[rf][cf][j] - m[rf][j]);
                        S[rf][cf][j] = p;
                        ps += p;
                    }
                    l[rf][j] = l[rf][j] * fac[rf][j] + ps;
                }
            #pragma unroll
            for (int rf = 0; rf < 2; ++rf)
                #pragma unroll
                for (int df = 0; df < 4; ++df)
                    #pragma unroll
                    for (int j = 0; j < 4; ++j)
                        O[rf][df][j] *= fac[rf][j];
        }

        // ---- P -> per-wave LDS tile, wave-local wait ----
        #pragma unroll
        for (int rf = 0; rf < 2; ++rf)
            #pragma unroll
            for (int cf = 0; cf < 4; ++cf)
                #pragma unroll
                for (int j = 0; j < 4; ++j)
                    P[w][rf * 16 + kgrp * 4 + j][cf * 16 + l15] = (bf16_t)S[rf][cf][j];
        asm volatile("s_waitcnt lgkmcnt(0)" ::: "memory");

        bf16x8 pa[2][2];
        #pragma unroll
        for (int rf = 0; rf < 2; ++rf)
            #pragma unroll
            for (int ks = 0; ks < 2; ++ks)
                pa[rf][ks] = *(const bf16x8*)&P[w][rf * 16 + l15][ks * 32 + kgrp * 8];

        // ---- PV ----
        __builtin_amdgcn_s_setprio(1);
        #pragma unroll
        for (int df = 0; df < 4; ++df) {
            const bf16_t* vrow = vbase + (size_t)(df * 16 + l15) * 1024 + kt0 + kgrp * 8;
            bf16x8 vf0 = *(const bf16x8*)vrow;
            bf16x8 vf1 = *(const bf16x8*)(vrow + 32);
            O[0][df] = mfma16x16x32(pa[0][0], vf0, O[0][df]);
            O[0][df] = mfma16x16x32(pa[0][1], vf1, O[0][df]);
            O[1][df] = mfma16x16x32(pa[1][0], vf0, O[1][df]);
            O[1][df] = mfma16x16x32(pa[1][1], vf1, O[1][df]);
        }
        __builtin_amdgcn_s_setprio(0);
    }

    // ---- merge phase ----
    __syncthreads();   // all waves done with P region

    #pragma unroll
    for (int rf = 0; rf < 2; ++rf)
        #pragma unroll
        for (int j = 0; j < 4; ++j) {
            float lv = l[rf][j];
            #pragma unroll
            for (int off = 1; off < 16; off <<= 1) lv += __shfl_xor(lv, off);
            l[rf][j] = lv;
        }

    #pragma unroll
    for (int rf = 0; rf < 2; ++rf)
        #pragma unroll
        for (int df = 0; df < 4; ++df)
            #pragma unroll
            for (int j = 0; j < 4; ++j)
                Omg[w][rf * 16 + kgrp * 4 + j][df * 16 + l15] = (bf16_t)O[rf][df][j];
    if (l15 == 0) {
        #pragma unroll
        for (int rf = 0; rf < 2; ++rf)
            #pragma unroll
            for (int j = 0; j < 4; ++j) {
                mmg[w * 32 + rf * 16 + kgrp * 4 + j] = m[rf][j];
                lmg[w * 32 + rf * 16 + kgrp * 4 + j] = l[rf][j];
            }
    }
    __syncthreads();

    {
        const int r  = tid >> 3;        // 0..31
        const int c0 = (tid & 7) * 8;   // 0..56
        float m0 = mmg[r], m1 = mmg[32 + r], m2 = mmg[64 + r], m3 = mmg[96 + r];
        float M = fmaxf(fmaxf(m0, m1), fmaxf(m2, m3));
        float f0 = __builtin_amdgcn_exp2f(m0 - M), f1 = __builtin_amdgcn_exp2f(m1 - M);
        float f2 = __builtin_amdgcn_exp2f(m2 - M), f3 = __builtin_amdgcn_exp2f(m3 - M);
        float ls = lmg[r] * f0 + lmg[32 + r] * f1 + lmg[64 + r] * f2 + lmg[96 + r] * f3;
        float inv = 1.0f / ls;
        bf16x8 o0 = *(const bf16x8*)&Omg[0][r][c0];
        bf16x8 o1 = *(const bf16x8*)&Omg[1][r][c0];
        bf16x8 o2 = *(const bf16x8*)&Omg[2][r][c0];
        bf16x8 o3 = *(const bf16x8*)&Omg[3][r][c0];
        bf16_t outv[8];
        #pragma unroll
        for (int i = 0; i < 8; ++i) {
            float acc = (float)o0[i] * f0 + (float)o1[i] * f1
                      + (float)o2[i] * f2 + (float)o3[i] * f3;
            outv[i] = (bf16_t)(acc * inv);
        }
        *(bf16x8*)&attout[(size_t)(h * 1024 + qw + r) * 512 + b * 64 + c0] = *(bf16x8*)outv;
    }
}

// ---------------------------------------------------------------------------
extern "C" void kernel_launch(void* const* d_in, const int* in_sizes, int n_in,
                              void* d_out, int out_size, void* d_ws, size_t ws_size,
                              hipStream_t stream) {
    const float* query = (const float*)d_in[0];
    const float* key   = (const float*)d_in[1];
    const float* value = (const float*)d_in[2];
    const int*   qmask = (const int*)d_in[3];
    const int*   kmask = (const int*)d_in[4];
    const float* Wq    = (const float*)d_in[5];
    const float* Wk    = (const float*)d_in[6];
    const float* Wv    = (const float*)d_in[7];
    const float* Wo    = (const float*)d_in[8];
    float* out = (float*)d_out;

    const size_t NELEM = (size_t)8 * 1024 * 512;
    bf16_t* qb  = (bf16_t*)d_ws;
    bf16_t* kb  = qb + NELEM;
    bf16_t* vtb = kb + NELEM;   // [b][d(512)][s(1024)]
    bf16_t* ab  = vtb + NELEM;

    gemm_qkv<<<dim3(64, 4, 3), dim3(256), 0, stream>>>(query, key, value, Wq, Wk, Wv, qb, kb, vtb);
    attn_flash<<<dim3(64, 32), dim3(256), 0, stream>>>(qb, kb, vtb, kmask, ab);
    gemm_out<<<dim3(64, 4), dim3(256), 0, stream>>>(ab, Wo, out, qmask);
}